// Round 18
// baseline (199.711 us; speedup 1.0000x reference)
//
#include <hip/hip_runtime.h>
#include <hip/hip_bf16.h>

#define BB 16
#define LL 2048
#define DD 128
#define SCALE 0.03125f   // 1/sqrt(1024)

#define QT 64            // fallback q-tile
#define QTM 128          // main/scores q-tile (512-thread blocks)
#define KT 64
#define NT (LL/KT)       // 32
#define SPLIT_S 4
#define SKT (NT/SPLIT_S) // 8
#define THREADS 256
#define TMAIN 512
#define NWG   (BB*(LL/QT))          // 512  (fallback grid)
#define NWG_S (BB*SPLIT_S*(LL/QTM)) // 1024 (scores grid)
#define NWG_V (BB*2*(LL/QTM))       // 512  (v3 grid: batch x qtile x d-half)

using bf16x8 = __attribute__((ext_vector_type(8))) short;
using f32x4  = __attribute__((ext_vector_type(4))) float;
using u16x4  = __attribute__((ext_vector_type(4))) unsigned short;
using u32x2  = __attribute__((ext_vector_type(2))) unsigned;
using u32x4  = __attribute__((ext_vector_type(4))) unsigned;
typedef unsigned long long u64;

__device__ __forceinline__ unsigned short f2bf(float f){
    __hip_bfloat16 h = __float2bfloat16(f);
    return *reinterpret_cast<unsigned short*>(&h);
}
__device__ __forceinline__ float bf2f(unsigned short u){
    union { unsigned u; float f; } a; a.u = ((unsigned)u) << 16;
    return a.f;
}
__device__ __forceinline__ unsigned pk2(float lo, float hi){
    return (unsigned)f2bf(lo) | ((unsigned)f2bf(hi) << 16);
}

// Mask layout: 0 = 4-byte int, 1 = 1-byte bool, 2 = 4-byte float.
__device__ __forceinline__ int detect_fl(const unsigned* m, int lane){
    unsigned hi = 0, nl = 0;
    #pragma unroll
    for (int i = 0; i < 16; ++i){
        unsigned d = m[lane*16 + i];
        hi |= (d & 0xFFFFFF00u);
        nl |= (d & 0xFEFEFEFEu);
    }
    unsigned long long bh = __ballot(hi != 0u);
    unsigned long long bn = __ballot(nl != 0u);
    return (bn != 0ull) ? 2 : ((bh != 0ull) ? 1 : 0);
}

__global__ void detect_mask(const unsigned* __restrict__ m, int* __restrict__ flag){
    int f = detect_fl(m, threadIdx.x & 63);
    if ((threadIdx.x & 63) == 0) flag[0] = f;
}

// bit-prepack (fallback paths only)
__global__ void prepack_mask(const unsigned char* __restrict__ m,
                             u64* __restrict__ mb){
    __shared__ int sfl;
    if (threadIdx.x < 64){
        int f = detect_fl((const unsigned*)m, threadIdx.x);
        if (threadIdx.x == 0) sfl = f;
    }
    __syncthreads();
    const int fl = sfl;
    int id = blockIdx.x * THREADS + threadIdx.x;
    u64 bits = 0;
    if (fl == 1){
        const uint4* mp = (const uint4*)(m + (size_t)id * 64);
        #pragma unroll
        for (int c = 0; c < 4; ++c){
            uint4 u = mp[c];
            unsigned wd[4] = {u.x, u.y, u.z, u.w};
            #pragma unroll
            for (int wi = 0; wi < 4; ++wi){
                #pragma unroll
                for (int b = 0; b < 4; ++b)
                    if ((wd[wi] >> (8*b)) & 0xFFu) bits |= 1ull << (c*16 + wi*4 + b);
            }
        }
    } else {
        const uint4* mp = (const uint4*)m + (size_t)id * 16;
        #pragma unroll
        for (int c = 0; c < 16; ++c){
            uint4 u = mp[c];
            if (u.x) bits |= 1ull << (c*4+0);
            if (u.y) bits |= 1ull << (c*4+1);
            if (u.z) bits |= 1ull << (c*4+2);
            if (u.w) bits |= 1ull << (c*4+3);
        }
    }
    mb[id] = bits;
}

// ---------------- 256-thread staging macros (fallback) ----------------
#define K_LOAD(T) { const float* kp_ = kbase + (size_t)(T)*KT*DD; \
    _Pragma("unroll") for (int i_ = 0; i_ < 8; ++i_) \
        kpre[i_] = *(const f32x4*)(kp_ + (i_*8 + r0)*DD + c4*4); }

#define K_WRITE() { _Pragma("unroll") for (int i_ = 0; i_ < 8; ++i_){ \
        int row_ = i_*8 + r0; int e_ = (c4*4) ^ (8*(row_ & 7)); \
        u16x4 pk_ = { f2bf(kpre[i_][0]), f2bf(kpre[i_][1]), f2bf(kpre[i_][2]), f2bf(kpre[i_][3]) }; \
        *(u16x4*)(&k_s[row_*DD + e_]) = pk_; } }

#define V_STAGE(T) { const float* vp_ = vbase + (size_t)(T)*KT*DD; \
    f32x4 vv_[8]; \
    _Pragma("unroll") for (int i_ = 0; i_ < 2; ++i_) \
        _Pragma("unroll") for (int rr_ = 0; rr_ < 4; ++rr_) \
            vv_[i_*4+rr_] = *(const f32x4*)(vp_ + ((r0 + 8*i_)*4 + rr_)*DD + c4*4); \
    _Pragma("unroll") for (int i_ = 0; i_ < 2; ++i_){ \
        int rb_ = (r0 + 8*i_)*4; int kk_ = rb_ ^ (8*(c4 & 7)); \
        _Pragma("unroll") for (int cc_ = 0; cc_ < 4; ++cc_){ \
            int d_ = c4*4 + cc_; \
            u16x4 pk_ = { f2bf(vv_[i_*4+0][cc_]), f2bf(vv_[i_*4+1][cc_]), \
                          f2bf(vv_[i_*4+2][cc_]), f2bf(vv_[i_*4+3][cc_]) }; \
            *(u16x4*)(&vT_s[d_*KT + kk_]) = pk_; } } }

#define M_LOADB(DST, T) { _Pragma("unroll") for (int r_ = 0; r_ < 4; ++r_) DST[r_] = mbB[r_*NT + (T)]; }

// ---------------- 512-thread staging macros ----------------
#define K_LOAD4(T) { const float* kp_ = kbase + (size_t)(T)*KT*DD; \
    _Pragma("unroll") for (int i_ = 0; i_ < 4; ++i_) \
        kpre[i_] = *(const f32x4*)(kp_ + (i_*16 + r0)*DD + c4*4); }

#define K_WRITE4() { _Pragma("unroll") for (int i_ = 0; i_ < 4; ++i_){ \
        int row_ = i_*16 + r0; int e_ = (c4*4) ^ (8*(row_ & 7)); \
        u16x4 pk_ = { f2bf(kpre[i_][0]), f2bf(kpre[i_][1]), f2bf(kpre[i_][2]), f2bf(kpre[i_][3]) }; \
        *(u16x4*)(&k_s[row_*DD + e_]) = pk_; } }

#define V_LOAD4(T) { const float* vp_ = vbase + (size_t)(T)*KT*DD; \
    _Pragma("unroll") for (int rr_ = 0; rr_ < 4; ++rr_) \
        vpre[rr_] = *(const f32x4*)(vp_ + (r0*4 + rr_)*DD + c4*4); }

#define V_WRITE4() { \
    _Pragma("unroll") for (int cc_ = 0; cc_ < 4; ++cc_){ \
        int d_ = c4*4 + cc_; \
        int key_ = (c4 & 7) ^ ((cc_ << 1) & 7); \
        int kk_ = (r0*4) ^ (8*key_); \
        u16x4 pk_ = { f2bf(vpre[0][cc_]), f2bf(vpre[1][cc_]), \
                      f2bf(vpre[2][cc_]), f2bf(vpre[3][cc_]) }; \
        *(u16x4*)(&vT_s[d_*KT + kk_]) = pk_; } }

// original orientation (fallback only)
#define QK_MFMA(ACC, CG) { \
    const int krow_ = (CG)*16 + ln15; \
    const unsigned short* kb_ = &k_s[krow_*DD]; \
    const int sw_ = 8*(krow_ & 7); \
    _Pragma("unroll") for (int c_ = 0; c_ < 4; ++c_){ \
        bf16x8 bf_ = *(const bf16x8*)(kb_ + ((c_*32 + g*8) ^ sw_)); \
        ACC = __builtin_amdgcn_mfma_f32_16x16x32_bf16(qa[c_], bf_, ACC, 0, 0, 0); } }

// SWAPPED: acc[r] = S[q=ln15][k=cg*16+4g+r]
#define QK_MFMA_SW(ACC, CG) { \
    const int krow_ = (CG)*16 + ln15; \
    const unsigned short* kb_ = &k_s[krow_*DD]; \
    const int sw_ = 8*(krow_ & 7); \
    _Pragma("unroll") for (int c_ = 0; c_ < 4; ++c_){ \
        bf16x8 bf_ = *(const bf16x8*)(kb_ + ((c_*32 + g*8) ^ sw_)); \
        ACC = __builtin_amdgcn_mfma_f32_16x16x32_bf16(bf_, qa[c_], ACC, 0, 0, 0); } }

#define Q_FRAGS() { \
    const float* qp_ = q + ((size_t)bb*LL + qw0 + ln15)*DD + g*8; \
    _Pragma("unroll") for (int c_ = 0; c_ < 4; ++c_){ \
        f32x4 x_ = *(const f32x4*)(qp_ + c_*32); \
        f32x4 y_ = *(const f32x4*)(qp_ + c_*32 + 4); \
        bf16x8 t_; \
        t_[0]=(short)f2bf(x_[0]); t_[1]=(short)f2bf(x_[1]); t_[2]=(short)f2bf(x_[2]); t_[3]=(short)f2bf(x_[3]); \
        t_[4]=(short)f2bf(y_[0]); t_[5]=(short)f2bf(y_[1]); t_[6]=(short)f2bf(y_[2]); t_[7]=(short)f2bf(y_[3]); \
        qa[c_] = t_; } }

// ===== kernel 1: scores — NT-mask QK + exp; pS stored DIRECT from regs =====
// Cached 8B stores (16 rows x 32B/instr); the 4 cg stores of a tile fully
// cover each 128B pS line -> no DRAM RMW on writeback. No LDS P-bounce.
template<int STOREP>
__global__ __launch_bounds__(TMAIN, 4) void scores(
    const float* __restrict__ q, const float* __restrict__ k,
    const unsigned char* __restrict__ maskb,
    float* __restrict__ lpart, unsigned short* __restrict__ pS)
{
    __shared__ __attribute__((aligned(16))) unsigned short k_s[KT*DD];   // 16 KB
    __shared__ int sfl;

    const int tid  = threadIdx.x;
    const int lane = tid & 63;
    const int ln15 = lane & 15;
    const int g    = lane >> 4;
    const int r0   = tid >> 5;
    const int c4   = tid & 31;
    const int w    = tid >> 6;

    if (tid < 64){
        int f = detect_fl((const unsigned*)maskb, tid);
        if (tid == 0) sfl = f;
    }

    const int hw    = blockIdx.x;
    const int bidx  = (hw & 7) * (NWG_S/8) + (hw >> 3);   // XCD-contiguous
    const int bb    = bidx >> 6;
    const int quart = (bidx >> 4) & 3;
    const int qt0   = (bidx & 15) * QTM;
    const int qw0   = qt0 + w*16;

    bf16x8 qa[4];
    Q_FRAGS();

    __syncthreads();
    const int fl = sfl;
    const size_t qrow = (size_t)bb*LL + qw0 + ln15;
    const unsigned char* mrowB = maskb + qrow*(size_t)LL;
    const unsigned char* mrowW = maskb + qrow*(size_t)LL*4;
    unsigned short* psrow = pS + qrow*(size_t)LL;

    const float* kbase = k + (size_t)bb*LL*DD;
    f32x4 kpre[4];
    u32x4 m4c[4], m4n[4];
    unsigned m1c[4], m1n[4];

#define MSK_LOAD(W4, B1, T) { \
    if (fl != 1){ _Pragma("unroll") for (int c_ = 0; c_ < 4; ++c_) \
        W4[c_] = __builtin_nontemporal_load((const u32x4*)(mrowW + ((size_t)(T)*KT + c_*16 + 4*g)*4)); } \
    else        { _Pragma("unroll") for (int c_ = 0; c_ < 4; ++c_) \
        B1[c_] = __builtin_nontemporal_load((const unsigned*)(mrowB + (size_t)(T)*KT + c_*16 + 4*g)); } }

    const int T0 = quart * SKT;
    float rs = 0.f;
    K_LOAD4(T0); MSK_LOAD(m4c, m1c, T0);
    for (int tt = 0; tt < SKT; ++tt){
        const int t = T0 + tt;
        __syncthreads();
        K_WRITE4();
        if (tt+1 < SKT){ K_LOAD4(t+1); MSK_LOAD(m4n, m1n, t+1); }
        __syncthreads();
        #pragma unroll
        for (int cg = 0; cg < 4; ++cg){
            f32x4 acc = {0.f, 0.f, 0.f, 0.f};
            QK_MFMA_SW(acc, cg);
            bool k0, k1, k2, k3;
            if (fl != 1){
                u32x4 u = m4c[cg];
                k0 = u[0] != 0u; k1 = u[1] != 0u; k2 = u[2] != 0u; k3 = u[3] != 0u;
            } else {
                unsigned u = m1c[cg];
                k0 = (u & 0xFFu) != 0u;       k1 = (u & 0xFF00u) != 0u;
                k2 = (u & 0xFF0000u) != 0u;   k3 = (u & 0xFF000000u) != 0u;
            }
            float p0 = k0 ? 0.f : __expf(acc[0] * SCALE);
            float p1 = k1 ? 0.f : __expf(acc[1] * SCALE);
            float p2 = k2 ? 0.f : __expf(acc[2] * SCALE);
            float p3 = k3 ? 0.f : __expf(acc[3] * SCALE);
            rs += (p0 + p1) + (p2 + p3);
            if (STOREP){
                u32x2 wv = { pk2(p0, p1), pk2(p2, p3) };
                *(u32x2*)(psrow + (size_t)t*KT + cg*16 + 4*g) = wv;
            }
        }
        #pragma unroll
        for (int c_ = 0; c_ < 4; ++c_){ m4c[c_] = m4n[c_]; m1c[c_] = m1n[c_]; }
    }
    rs += __shfl_xor(rs, 16);
    rs += __shfl_xor(rs, 32);
    if (lane < 16)
        lpart[(size_t)quart*BB*LL + (size_t)bb*LL + qw0 + lane] = rs;
#undef MSK_LOAD
}

// ===== kernel 2 V3b (D-split, half-V staging): attn + out directly =====
__global__ __launch_bounds__(TMAIN, 4) void attn_main_v3(
    const float* __restrict__ v, const unsigned short* __restrict__ pS,
    const float* __restrict__ lpart,
    float* __restrict__ attn, float* __restrict__ out)
{
    __shared__ __attribute__((aligned(16))) unsigned short vT_s[64*64];   // 8 KB (my d-half)

    const int tid  = threadIdx.x;
    const int lane = tid & 63;
    const int ln15 = lane & 15;
    const int g    = lane >> 4;
    const int kr2  = tid >> 4;             // 0..31 (2 k-rows each)
    const int dc   = tid & 15;             // 0..15 (4 local d-cols each)
    const int w    = tid >> 6;

    const int hw   = blockIdx.x;
    const int bidx = (hw & 7) * (NWG_V/8) + (hw >> 3);
    const int bb   = bidx >> 5;
    const int rem  = bidx & 31;
    const int dh   = rem & 1;              // d-half: cols [dh*64, dh*64+64)
    const int qt0  = (rem >> 1) * QTM;
    const int qw0  = qt0 + w*16;

    float invlA[4], invlE[4];
    #pragma unroll
    for (int i = 0; i < 4; ++i){
        float sA = 0.f, sE = 0.f;
        #pragma unroll
        for (int sl = 0; sl < SPLIT_S; ++sl){
            sA += lpart[(size_t)sl*BB*LL + (size_t)bb*LL + qw0 + i*4 + g];
            sE += lpart[(size_t)sl*BB*LL + (size_t)bb*LL + qw0 + 4*g + i];
        }
        invlA[i] = 1.0f / sA;
        invlE[i] = 1.0f / sE;
    }

    const float* vbase = v + (size_t)bb*LL*DD + dh*64;
    f32x4 vh[2];

#define VH_LOAD(T) { \
    _Pragma("unroll") for (int j_ = 0; j_ < 2; ++j_) \
        vh[j_] = *(const f32x4*)(vbase + ((size_t)(T)*KT + kr2*2 + j_)*DD + dc*4); }

#define VH_WRITE() { \
    _Pragma("unroll") for (int cc_ = 0; cc_ < 4; ++cc_){ \
        int d_ = dc*4 + cc_; \
        int key_ = (dc & 7) ^ ((cc_ << 1) & 7); \
        int kk_ = (kr2*2) ^ (8*key_); \
        unsigned pv_ = pk2(vh[0][cc_], vh[1][cc_]); \
        *(unsigned*)(&vT_s[d_*64 + kk_]) = pv_; } }

    const unsigned short* prow = pS + ((size_t)bb*LL + qw0 + ln15)*(size_t)LL;
    size_t arow_off[4];
    #pragma unroll
    for (int i = 0; i < 4; ++i)
        arow_off[i] = ((size_t)bb*LL + qw0 + i*4 + g)*(size_t)LL;

    f32x4 oacc[4];
    #pragma unroll
    for (int d8 = 0; d8 < 4; ++d8) oacc[d8] = (f32x4){0.f, 0.f, 0.f, 0.f};

    bf16x8 pa0c, pa1c, pa0n, pa1n;

    VH_LOAD(0);
    pa0c = *(const bf16x8*)(prow + 8*g);
    pa1c = *(const bf16x8*)(prow + 32 + 8*g);
    for (int t = 0; t < NT; ++t){
        __syncthreads();
        VH_WRITE();
        if (t+1 < NT){
            VH_LOAD(t+1);
            pa0n = *(const bf16x8*)(prow + (size_t)(t+1)*KT + 8*g);
            pa1n = *(const bf16x8*)(prow + (size_t)(t+1)*KT + 32 + 8*g);
        }
        __syncthreads();
        if ((t >> 4) == dh){
            #pragma unroll
            for (int i = 0; i < 4; ++i){
                u32x2 pb = *(const u32x2*)(pS + arow_off[i] + (size_t)t*KT + ln15*4);
                f32x4 val = { bf2f((unsigned short)(pb[0] & 0xFFFFu)) * invlA[i],
                              bf2f((unsigned short)(pb[0] >> 16))     * invlA[i],
                              bf2f((unsigned short)(pb[1] & 0xFFFFu)) * invlA[i],
                              bf2f((unsigned short)(pb[1] >> 16))     * invlA[i] };
                __builtin_nontemporal_store(val,
                    (f32x4*)(attn + arow_off[i] + (size_t)t*KT + ln15*4));
            }
        }
        #pragma unroll
        for (int d8 = 0; d8 < 4; ++d8){
            const int d_ = d8*16 + ln15;                 // local d
            const unsigned short* vb = &vT_s[d_*64];
            const int ev = 8*(((4*d8 + (ln15 >> 2)) & 7) ^ ((ln15 & 3) << 1));
            bf16x8 b0 = *(const bf16x8*)(vb + ((g*8) ^ ev));
            bf16x8 b1 = *(const bf16x8*)(vb + ((32 + g*8) ^ ev));
            oacc[d8] = __builtin_amdgcn_mfma_f32_16x16x32_bf16(pa0c, b0, oacc[d8], 0, 0, 0);
            oacc[d8] = __builtin_amdgcn_mfma_f32_16x16x32_bf16(pa1c, b1, oacc[d8], 0, 0, 0);
        }
        pa0c = pa0n; pa1c = pa1n;
    }
#undef VH_LOAD
#undef VH_WRITE

    #pragma unroll
    for (int d8 = 0; d8 < 4; ++d8){
        #pragma unroll
        for (int r = 0; r < 4; ++r){
            out[((size_t)bb*LL + qw0 + 4*g + r)*DD + dh*64 + d8*16 + ln15]
                = oacc[d8][r] * invlE[r];
        }
    }
}

// ===== old kernel 2 (r11-proven fallback): QK in-kernel, K-split =====
template<int NS>
__global__ __launch_bounds__(TMAIN, 4) void attn_main(
    const float* __restrict__ q, const float* __restrict__ k, const float* __restrict__ v,
    const u64* __restrict__ mb, const float* __restrict__ lpart,
    float* __restrict__ attn, float* __restrict__ pO)
{
    __shared__ __attribute__((aligned(16))) unsigned short k_s[KT*DD];
    __shared__ __attribute__((aligned(16))) unsigned short vT_s[DD*KT];
    __shared__ __attribute__((aligned(16))) unsigned p_u32[8*512];

    const int tid  = threadIdx.x;
    const int w    = tid >> 6;
    const int lane = tid & 63;
    const int ln15 = lane & 15;
    const int g    = lane >> 4;
    const int r0   = tid >> 5;
    const int c4   = tid & 31;

    const int NWGM = BB*NS*(LL/QTM);
    const int hw   = blockIdx.x;
    const int bidx = (hw & 7) * (NWGM/8) + (hw >> 3);
    const int perb = NS*(LL/QTM);
    const int bb   = bidx / perb;
    const int rem  = bidx % perb;
    const int part = rem >> 4;
    const int qt0  = (rem & 15) * QTM;
    const int qw0  = qt0 + w*16;

    bf16x8 qa[4];
    Q_FRAGS();

    const size_t qrow = (size_t)bb*LL + qw0 + ln15;
    const u64* mrow_bits = mb + qrow * NT;
    float invl;
    {
        float s = 0.f;
        #pragma unroll
        for (int sl = 0; sl < SPLIT_S; ++sl)
            s += lpart[(size_t)sl*BB*LL + qrow];
        invl = 1.0f / s;
    }

    const float* kbase = k + (size_t)bb*LL*DD;
    const float* vbase = v + (size_t)bb*LL*DD;
    f32x4 kpre[4];
    f32x4 vpre[4];
    u64 mc = 0, mn = 0;

    f32x4 oacc[8];
    #pragma unroll
    for (int d8 = 0; d8 < 8; ++d8) oacc[d8] = (f32x4){0.f, 0.f, 0.f, 0.f};

    unsigned* pw = &p_u32[w*512];

    const int HKTN = NT/NS;
    const int T0 = part * HKTN;
    K_LOAD4(T0); V_LOAD4(T0); mc = mrow_bits[T0];
    for (int tt = 0; tt < HKTN; ++tt){
        const int t = T0 + tt;
        __syncthreads();
        K_WRITE4(); V_WRITE4();
        if (tt+1 < HKTN){ K_LOAD4(t+1); V_LOAD4(t+1); mn = mrow_bits[t+1]; }
        __syncthreads();
        #pragma unroll
        for (int cg = 0; cg < 4; ++cg){
            f32x4 acc = {0.f, 0.f, 0.f, 0.f};
            QK_MFMA_SW(acc, cg);
            const int kb0 = cg*16 + 4*g;
            const unsigned nib = (unsigned)(mc >> kb0) & 0xFu;
            f32x4 pv;
            #pragma unroll
            for (int r = 0; r < 4; ++r)
                pv[r] = ((nib >> r) & 1u) ? 0.f : __expf(acc[r] * SCALE) * invl;
            const int m  = cg*4 + g;
            const int mp = (m + ln15) & 15;
            u32x2 wv = { pk2(pv[0], pv[1]), pk2(pv[2], pv[3]) };
            *(u32x2*)(&pw[ln15*32 + mp*2]) = wv;
        }
        #pragma unroll
        for (int it = 0; it < 4; ++it){
            const int rl = it*4 + g;
            u32x2 pb = *(const u32x2*)(&pw[rl*32 + (((ln15 + rl) & 15)*2)]);
            f32x4 val = { bf2f((unsigned short)(pb[0] & 0xFFFFu)),
                          bf2f((unsigned short)(pb[0] >> 16)),
                          bf2f((unsigned short)(pb[1] & 0xFFFFu)),
                          bf2f((unsigned short)(pb[1] >> 16)) };
            __builtin_nontemporal_store(val,
                (f32x4*)(attn + ((size_t)bb*LL + qw0 + rl)*(size_t)LL + t*KT + ln15*4));
        }
        const unsigned* prow_ = &pw[ln15*32];
        u32x2 a00 = *(const u32x2*)(&prow_[(((2*g  ) + ln15) & 15)*2]);
        u32x2 a01 = *(const u32x2*)(&prow_[(((2*g+1) + ln15) & 15)*2]);
        u32x2 a10 = *(const u32x2*)(&prow_[(((8+2*g ) + ln15) & 15)*2]);
        u32x2 a11 = *(const u32x2*)(&prow_[(((9+2*g ) + ln15) & 15)*2]);
        union { unsigned u[4]; bf16x8 v8; } A0, A1;
        A0.u[0]=a00[0]; A0.u[1]=a00[1]; A0.u[2]=a01[0]; A0.u[3]=a01[1];
        A1.u[0]=a10[0]; A1.u[1]=a10[1]; A1.u[2]=a11[0]; A1.u[3]=a11[1];
        const bf16x8 pa0 = A0.v8, pa1 = A1.v8;
        #pragma unroll
        for (int d8 = 0; d8 < 8; ++d8){
            const int d = d8*16 + ln15;
            const unsigned short* vb = &vT_s[d*KT];
            const int ev = 8*((((4*d8 + (ln15 >> 2)) & 7)) ^ ((ln15 & 3) << 1));
            bf16x8 b0 = *(const bf16x8*)(vb + ((g*8) ^ ev));
            bf16x8 b1 = *(const bf16x8*)(vb + ((32 + g*8) ^ ev));
            oacc[d8] = __builtin_amdgcn_mfma_f32_16x16x32_bf16(pa0, b0, oacc[d8], 0, 0, 0);
            oacc[d8] = __builtin_amdgcn_mfma_f32_16x16x32_bf16(pa1, b1, oacc[d8], 0, 0, 0);
        }
        mc = mn;
    }

    float* po = pO + (size_t)part*BB*LL*DD;
    #pragma unroll
    for (int d8 = 0; d8 < 8; ++d8){
        #pragma unroll
        for (int r = 0; r < 4; ++r){
            po[((size_t)bb*LL + qw0 + 4*g + r)*DD + d8*16 + ln15] = oacc[d8][r];
        }
    }
}

template<int NS>
__global__ void combine_out(const float* __restrict__ pO, float* __restrict__ out){
    size_t i = ((size_t)blockIdx.x*THREADS + threadIdx.x) * 4;
    f32x4 s = *(const f32x4*)(pO + i);
    #pragma unroll
    for (int sl = 1; sl < NS; ++sl)
        s += *(const f32x4*)(pO + (size_t)sl*BB*LL*DD + i);
    *(f32x4*)(out + i) = s;
}

// ================= fallback: fused two-pass (unswapped) =================
template<int USE_BITS>
__global__ __launch_bounds__(THREADS, 3) void attn_fused(
    const float* __restrict__ q, const float* __restrict__ k, const float* __restrict__ v,
    const unsigned char* __restrict__ maskb, const int* __restrict__ flagp,
    const u64* __restrict__ mb,
    float* __restrict__ out, float* __restrict__ attn)
{
    __shared__ __attribute__((aligned(16))) unsigned short k_s[KT*DD];
    __shared__ __attribute__((aligned(16))) unsigned short vT_s[DD*KT];
    __shared__ __attribute__((aligned(16))) unsigned short p_bf[4*16*64];

    const int tid  = threadIdx.x;
    const int w    = tid >> 6;
    const int lane = tid & 63;
    const int ln15 = lane & 15;
    const int g    = lane >> 4;
    const int r0   = tid >> 5;
    const int c4   = tid & 31;

    const int bidx = blockIdx.x;
    const int bb   = bidx >> 5;
    const int qt0  = (bidx & 31) * QT;
    const int qw0  = qt0 + w*16;

    int msh = 0, madd = 0;
    if (!USE_BITS){
        const int mflag = flagp[0];
        msh  = (mflag == 1) ? 0 : 2;
        madd = (mflag == 2) ? 3 : 0;
    }

    bf16x8 qa[4];
    Q_FRAGS();

    size_t mrow[4];
    const u64* mbB = mb + ((size_t)bb*LL + qw0 + 4*g) * NT;
    #pragma unroll
    for (int r = 0; r < 4; ++r)
        mrow[r] = ((size_t)bb*LL + qw0 + 4*g + r) * (size_t)LL;

    const float* kbase = k + (size_t)bb*LL*DD;
    const float* vbase = v + (size_t)bb*LL*DD;

    f32x4 kpre[8];
    u64 mc[4] = {0,0,0,0}, mn[4] = {0,0,0,0};

    float rs[4] = {0.f, 0.f, 0.f, 0.f};
    K_LOAD(0); if (USE_BITS) M_LOADB(mc, 0);
    for (int t = 0; t < NT; ++t){
        __syncthreads();
        K_WRITE();
        if (t+1 < NT){ K_LOAD(t+1); if (USE_BITS) M_LOADB(mn, t+1); }
        __syncthreads();
        #pragma unroll
        for (int cg = 0; cg < 4; ++cg){
            f32x4 acc = {0.f, 0.f, 0.f, 0.f};
            QK_MFMA(acc, cg);
            const int kc = cg*16 + ln15;
            #pragma unroll
            for (int r = 0; r < 4; ++r){
                bool msk;
                if (USE_BITS) msk = (mc[r] >> kc) & 1ull;
                else          msk = maskb[((mrow[r] + t*KT + kc) << msh) + madd] != 0;
                rs[r] += msk ? 0.f : __expf(acc[r] * SCALE);
            }
        }
        if (USE_BITS){
            #pragma unroll
            for (int r = 0; r < 4; ++r) mc[r] = mn[r];
        }
    }

    float invl[4];
    #pragma unroll
    for (int r = 0; r < 4; ++r){
        float s = rs[r];
        s += __shfl_xor(s, 1); s += __shfl_xor(s, 2);
        s += __shfl_xor(s, 4); s += __shfl_xor(s, 8);
        invl[r] = 1.0f / s;
    }

    f32x4 oacc[8];
    #pragma unroll
    for (int d8 = 0; d8 < 8; ++d8) oacc[d8] = (f32x4){0.f, 0.f, 0.f, 0.f};

    unsigned short* pw = &p_bf[w*1024];
    const int w4 = ln15 >> 2;

    K_LOAD(0); if (USE_BITS) M_LOADB(mc, 0);
    for (int t = 0; t < NT; ++t){
        __syncthreads();
        K_WRITE();
        V_STAGE(t);
        if (t+1 < NT){ K_LOAD(t+1); if (USE_BITS) M_LOADB(mn, t+1); }
        __syncthreads();
        #pragma unroll
        for (int cg = 0; cg < 4; ++cg){
            f32x4 acc = {0.f, 0.f, 0.f, 0.f};
            QK_MFMA(acc, cg);
            const int kc = cg*16 + ln15;
            #pragma unroll
            for (int r = 0; r < 4; ++r){
                bool msk;
                if (USE_BITS) msk = (mc[r] >> kc) & 1ull;
                else          msk = maskb[((mrow[r] + t*KT + kc) << msh) + madd] != 0;
                float p = msk ? 0.f : __expf(acc[r] * SCALE) * invl[r];
                pw[(4*g + r)*64 + (kc ^ (g << 4))] = f2bf(p);
            }
        }
        #pragma unroll
        for (int it = 0; it < 4; ++it){
            int row = it*4 + g;
            u16x4 pb = *(const u16x4*)(&pw[row*64 + ((ln15*4) ^ (it << 4))]);
            f32x4 val = { bf2f(pb[0]), bf2f(pb[1]), bf2f(pb[2]), bf2f(pb[3]) };
            *(f32x4*)(&attn[((size_t)bb*LL + qw0 + row)*(size_t)LL + t*KT + ln15*4]) = val;
        }
        const unsigned short* par = pw + ln15*64;
        bf16x8 pa0 = *(const bf16x8*)(par + ((g*8)      ^ (w4 << 4)));
        bf16x8 pa1 = *(const bf16x8*)(par + ((32 + g*8) ^ (w4 << 4)));
        #pragma unroll
        for (int d8 = 0; d8 < 8; ++d8){
            const int d = d8*16 + ln15;
            const unsigned short* vb = &vT_s[d*KT];
            const int ev = 8*((4*d8 + (ln15 >> 2)) & 7);
            bf16x8 b0 = *(const bf16x8*)(vb + ((g*8) ^ ev));
            bf16x8 b1 = *(const bf16x8*)(vb + ((32 + g*8) ^ ev));
            oacc[d8] = __builtin_amdgcn_mfma_f32_16x16x32_bf16(pa0, b0, oacc[d8], 0, 0, 0);
            oacc[d8] = __builtin_amdgcn_mfma_f32_16x16x32_bf16(pa1, b1, oacc[d8], 0, 0, 0);
        }
        if (USE_BITS){
            #pragma unroll
            for (int r = 0; r < 4; ++r) mc[r] = mn[r];
        }
    }

    #pragma unroll
    for (int d8 = 0; d8 < 8; ++d8){
        #pragma unroll
        for (int r = 0; r < 4; ++r){
            out[((size_t)bb*LL + qw0 + 4*g + r)*DD + d8*16 + ln15] = oacc[d8][r];
        }
    }
}

extern "C" void kernel_launch(void* const* d_in, const int* in_sizes, int n_in,
                              void* d_out, int out_size, void* d_ws, size_t ws_size,
                              hipStream_t stream)
{
    const float* q = (const float*)d_in[0];
    const float* k = (const float*)d_in[1];
    const float* v = (const float*)d_in[2];
    const unsigned char* mask = (const unsigned char*)d_in[3];

    float* out  = (float*)d_out;
    float* attn = out + (size_t)BB*LL*DD;

    const size_t oO      = (size_t)BB*LL*DD*sizeof(float);         // 16.8 MB / partial
    const size_t bits_sz = (size_t)BB*LL*NT*sizeof(u64);           // 8.39 MB
    const size_t off_lp  = 256 + bits_sz;
    const size_t lp_sz   = (size_t)SPLIT_S*BB*LL*sizeof(float);    // 512 KB
    const size_t off_pS  = off_lp + lp_sz;
    const size_t pS_sz   = (size_t)BB*LL*LL*sizeof(unsigned short);// 134.2 MB
    const size_t need_v3 = off_pS + pS_sz;                         // ~143.3 MB
    const size_t off_pOo = off_pS;
    const size_t need_o4 = off_pOo + 4*oO;                         // ~75.9 MB (r11-proven)
    const size_t need_o2 = off_pOo + 2*oO;                         // ~42.4 MB (r10-proven)
    const size_t need_bits = off_lp;

    int*   flag  = (int*)d_ws;
    u64*   mb    = (u64*)((char*)d_ws + 256);
    float* lpart = (float*)((char*)d_ws + off_lp);
    unsigned short* pS = (unsigned short*)((char*)d_ws + off_pS);
    float* pOo   = (float*)((char*)d_ws + off_pOo);

    if (ws_size >= need_v3){
        scores<1><<<NWG_S, TMAIN, 0, stream>>>(q, k, mask, lpart, pS);
        attn_main_v3<<<NWG_V, TMAIN, 0, stream>>>(v, pS, lpart, attn, out);
    } else if (ws_size >= need_o4){
        prepack_mask<<<(BB*LL*NT)/THREADS, THREADS, 0, stream>>>(mask, mb);
        scores<0><<<NWG_S, TMAIN, 0, stream>>>(q, k, mask, lpart, pS);
        attn_main<4><<<BB*4*(LL/QTM), TMAIN, 0, stream>>>(q, k, v, mb, lpart, attn, pOo);
        combine_out<4><<<(BB*LL*DD)/(4*THREADS), THREADS, 0, stream>>>(pOo, out);
    } else if (ws_size >= need_o2){
        prepack_mask<<<(BB*LL*NT)/THREADS, THREADS, 0, stream>>>(mask, mb);
        scores<0><<<NWG_S, TMAIN, 0, stream>>>(q, k, mask, lpart, pS);
        attn_main<2><<<BB*2*(LL/QTM), TMAIN, 0, stream>>>(q, k, v, mb, lpart, attn, pOo);
        combine_out<2><<<(BB*LL*DD)/(4*THREADS), THREADS, 0, stream>>>(pOo, out);
    } else if (ws_size >= need_bits){
        detect_mask<<<1, 64, 0, stream>>>((const unsigned*)mask, flag);
        prepack_mask<<<(BB*LL*NT)/THREADS, THREADS, 0, stream>>>(mask, mb);
        attn_fused<1><<<NWG, THREADS, 0, stream>>>(q, k, v, mask, flag, mb, out, attn);
    } else {
        detect_mask<<<1, 64, 0, stream>>>((const unsigned*)mask, flag);
        attn_fused<0><<<NWG, THREADS, 0, stream>>>(q, k, v, mask, flag, mb, out, attn);
    }
}

// Round 19
// 187.606 us; speedup vs baseline: 1.0645x; 1.0645x over previous
//
#include <hip/hip_runtime.h>
#include <hip/hip_bf16.h>

#define BB 16
#define LL 2048
#define DD 128
#define SCALE 0.03125f   // 1/sqrt(1024)

#define QT 64            // fallback q-tile
#define QTM 128          // main/scores q-tile (512-thread blocks)
#define KT 64
#define NT (LL/KT)       // 32
#define SPLIT_S 4
#define SKT (NT/SPLIT_S) // 8
#define THREADS 256
#define TMAIN 512
#define NWG   (BB*(LL/QT))          // 512  (fallback grid)
#define NWG_S (BB*SPLIT_S*(LL/QTM)) // 1024 (scores grid)
#define NWG_V (BB*2*(LL/QTM))       // 512  (v3 grid: batch x qtile x d-half)

using bf16x8 = __attribute__((ext_vector_type(8))) short;
using f32x4  = __attribute__((ext_vector_type(4))) float;
using u16x4  = __attribute__((ext_vector_type(4))) unsigned short;
using u32x2  = __attribute__((ext_vector_type(2))) unsigned;
using u32x4  = __attribute__((ext_vector_type(4))) unsigned;
typedef unsigned long long u64;

__device__ __forceinline__ unsigned short f2bf(float f){
    __hip_bfloat16 h = __float2bfloat16(f);
    return *reinterpret_cast<unsigned short*>(&h);
}
__device__ __forceinline__ float bf2f(unsigned short u){
    union { unsigned u; float f; } a; a.u = ((unsigned)u) << 16;
    return a.f;
}
__device__ __forceinline__ unsigned pk2(float lo, float hi){
    return (unsigned)f2bf(lo) | ((unsigned)f2bf(hi) << 16);
}

// Mask layout: 0 = 4-byte int, 1 = 1-byte bool, 2 = 4-byte float.
__device__ __forceinline__ int detect_fl(const unsigned* m, int lane){
    unsigned hi = 0, nl = 0;
    #pragma unroll
    for (int i = 0; i < 16; ++i){
        unsigned d = m[lane*16 + i];
        hi |= (d & 0xFFFFFF00u);
        nl |= (d & 0xFEFEFEFEu);
    }
    unsigned long long bh = __ballot(hi != 0u);
    unsigned long long bn = __ballot(nl != 0u);
    return (bn != 0ull) ? 2 : ((bh != 0ull) ? 1 : 0);
}

__global__ void detect_mask(const unsigned* __restrict__ m, int* __restrict__ flag){
    int f = detect_fl(m, threadIdx.x & 63);
    if ((threadIdx.x & 63) == 0) flag[0] = f;
}

// bit-prepack (fallback paths only)
__global__ void prepack_mask(const unsigned char* __restrict__ m,
                             u64* __restrict__ mb){
    __shared__ int sfl;
    if (threadIdx.x < 64){
        int f = detect_fl((const unsigned*)m, threadIdx.x);
        if (threadIdx.x == 0) sfl = f;
    }
    __syncthreads();
    const int fl = sfl;
    int id = blockIdx.x * THREADS + threadIdx.x;
    u64 bits = 0;
    if (fl == 1){
        const uint4* mp = (const uint4*)(m + (size_t)id * 64);
        #pragma unroll
        for (int c = 0; c < 4; ++c){
            uint4 u = mp[c];
            unsigned wd[4] = {u.x, u.y, u.z, u.w};
            #pragma unroll
            for (int wi = 0; wi < 4; ++wi){
                #pragma unroll
                for (int b = 0; b < 4; ++b)
                    if ((wd[wi] >> (8*b)) & 0xFFu) bits |= 1ull << (c*16 + wi*4 + b);
            }
        }
    } else {
        const uint4* mp = (const uint4*)m + (size_t)id * 16;
        #pragma unroll
        for (int c = 0; c < 16; ++c){
            uint4 u = mp[c];
            if (u.x) bits |= 1ull << (c*4+0);
            if (u.y) bits |= 1ull << (c*4+1);
            if (u.z) bits |= 1ull << (c*4+2);
            if (u.w) bits |= 1ull << (c*4+3);
        }
    }
    mb[id] = bits;
}

// ---------------- 256-thread staging macros (fallback) ----------------
#define K_LOAD(T) { const float* kp_ = kbase + (size_t)(T)*KT*DD; \
    _Pragma("unroll") for (int i_ = 0; i_ < 8; ++i_) \
        kpre[i_] = *(const f32x4*)(kp_ + (i_*8 + r0)*DD + c4*4); }

#define K_WRITE() { _Pragma("unroll") for (int i_ = 0; i_ < 8; ++i_){ \
        int row_ = i_*8 + r0; int e_ = (c4*4) ^ (8*(row_ & 7)); \
        u16x4 pk_ = { f2bf(kpre[i_][0]), f2bf(kpre[i_][1]), f2bf(kpre[i_][2]), f2bf(kpre[i_][3]) }; \
        *(u16x4*)(&k_s[row_*DD + e_]) = pk_; } }

#define V_STAGE(T) { const float* vp_ = vbase + (size_t)(T)*KT*DD; \
    f32x4 vv_[8]; \
    _Pragma("unroll") for (int i_ = 0; i_ < 2; ++i_) \
        _Pragma("unroll") for (int rr_ = 0; rr_ < 4; ++rr_) \
            vv_[i_*4+rr_] = *(const f32x4*)(vp_ + ((r0 + 8*i_)*4 + rr_)*DD + c4*4); \
    _Pragma("unroll") for (int i_ = 0; i_ < 2; ++i_){ \
        int rb_ = (r0 + 8*i_)*4; int kk_ = rb_ ^ (8*(c4 & 7)); \
        _Pragma("unroll") for (int cc_ = 0; cc_ < 4; ++cc_){ \
            int d_ = c4*4 + cc_; \
            u16x4 pk_ = { f2bf(vv_[i_*4+0][cc_]), f2bf(vv_[i_*4+1][cc_]), \
                          f2bf(vv_[i_*4+2][cc_]), f2bf(vv_[i_*4+3][cc_]) }; \
            *(u16x4*)(&vT_s[d_*KT + kk_]) = pk_; } } }

#define M_LOADB(DST, T) { _Pragma("unroll") for (int r_ = 0; r_ < 4; ++r_) DST[r_] = mbB[r_*NT + (T)]; }

// ---------------- 512-thread staging macros ----------------
#define K_LOAD4(T) { const float* kp_ = kbase + (size_t)(T)*KT*DD; \
    _Pragma("unroll") for (int i_ = 0; i_ < 4; ++i_) \
        kpre[i_] = *(const f32x4*)(kp_ + (i_*16 + r0)*DD + c4*4); }

#define K_WRITE4() { _Pragma("unroll") for (int i_ = 0; i_ < 4; ++i_){ \
        int row_ = i_*16 + r0; int e_ = (c4*4) ^ (8*(row_ & 7)); \
        u16x4 pk_ = { f2bf(kpre[i_][0]), f2bf(kpre[i_][1]), f2bf(kpre[i_][2]), f2bf(kpre[i_][3]) }; \
        *(u16x4*)(&k_s[row_*DD + e_]) = pk_; } }

#define V_LOAD4(T) { const float* vp_ = vbase + (size_t)(T)*KT*DD; \
    _Pragma("unroll") for (int rr_ = 0; rr_ < 4; ++rr_) \
        vpre[rr_] = *(const f32x4*)(vp_ + (r0*4 + rr_)*DD + c4*4); }

#define V_WRITE4() { \
    _Pragma("unroll") for (int cc_ = 0; cc_ < 4; ++cc_){ \
        int d_ = c4*4 + cc_; \
        int key_ = (c4 & 7) ^ ((cc_ << 1) & 7); \
        int kk_ = (r0*4) ^ (8*key_); \
        u16x4 pk_ = { f2bf(vpre[0][cc_]), f2bf(vpre[1][cc_]), \
                      f2bf(vpre[2][cc_]), f2bf(vpre[3][cc_]) }; \
        *(u16x4*)(&vT_s[d_*KT + kk_]) = pk_; } }

// original orientation (fallback only)
#define QK_MFMA(ACC, CG) { \
    const int krow_ = (CG)*16 + ln15; \
    const unsigned short* kb_ = &k_s[krow_*DD]; \
    const int sw_ = 8*(krow_ & 7); \
    _Pragma("unroll") for (int c_ = 0; c_ < 4; ++c_){ \
        bf16x8 bf_ = *(const bf16x8*)(kb_ + ((c_*32 + g*8) ^ sw_)); \
        ACC = __builtin_amdgcn_mfma_f32_16x16x32_bf16(qa[c_], bf_, ACC, 0, 0, 0); } }

// SWAPPED: acc[r] = S[q=ln15][k=cg*16+4g+r]
#define QK_MFMA_SW(ACC, CG) { \
    const int krow_ = (CG)*16 + ln15; \
    const unsigned short* kb_ = &k_s[krow_*DD]; \
    const int sw_ = 8*(krow_ & 7); \
    _Pragma("unroll") for (int c_ = 0; c_ < 4; ++c_){ \
        bf16x8 bf_ = *(const bf16x8*)(kb_ + ((c_*32 + g*8) ^ sw_)); \
        ACC = __builtin_amdgcn_mfma_f32_16x16x32_bf16(bf_, qa[c_], ACC, 0, 0, 0); } }

#define Q_FRAGS() { \
    const float* qp_ = q + ((size_t)bb*LL + qw0 + ln15)*DD + g*8; \
    _Pragma("unroll") for (int c_ = 0; c_ < 4; ++c_){ \
        f32x4 x_ = *(const f32x4*)(qp_ + c_*32); \
        f32x4 y_ = *(const f32x4*)(qp_ + c_*32 + 4); \
        bf16x8 t_; \
        t_[0]=(short)f2bf(x_[0]); t_[1]=(short)f2bf(x_[1]); t_[2]=(short)f2bf(x_[2]); t_[3]=(short)f2bf(x_[3]); \
        t_[4]=(short)f2bf(y_[0]); t_[5]=(short)f2bf(y_[1]); t_[6]=(short)f2bf(y_[2]); t_[7]=(short)f2bf(y_[3]); \
        qa[c_] = t_; } }

// ===== kernel 1: scores — NT-mask QK + exp; partial row sums + optional P~ =====
// Mask reads are NONTEMPORAL (via ext-vector u32x4): the 268 MB stream must
// not evict pS (134 MB) from L3. pS goes through the per-wave LDS bounce so
// each store instr covers 4 rows x 128B contiguous (r18 showed direct 16x32B
// scattered stores cost +12us).
template<int STOREP>
__global__ __launch_bounds__(TMAIN, 4) void scores(
    const float* __restrict__ q, const float* __restrict__ k,
    const unsigned char* __restrict__ maskb,
    float* __restrict__ lpart, unsigned short* __restrict__ pS)
{
    __shared__ __attribute__((aligned(16))) unsigned short k_s[KT*DD];   // 16 KB
    __shared__ __attribute__((aligned(16))) unsigned p_u32[8*512];       // 16 KB
    __shared__ int sfl;

    const int tid  = threadIdx.x;
    const int w    = tid >> 6;
    const int lane = tid & 63;
    const int ln15 = lane & 15;
    const int g    = lane >> 4;
    const int r0   = tid >> 5;
    const int c4   = tid & 31;

    if (tid < 64){
        int f = detect_fl((const unsigned*)maskb, tid);
        if (tid == 0) sfl = f;
    }

    const int hw    = blockIdx.x;
    const int bidx  = (hw & 7) * (NWG_S/8) + (hw >> 3);   // XCD-contiguous
    const int bb    = bidx >> 6;
    const int quart = (bidx >> 4) & 3;
    const int qt0   = (bidx & 15) * QTM;
    const int qw0   = qt0 + w*16;

    bf16x8 qa[4];
    Q_FRAGS();

    __syncthreads();
    const int fl = sfl;
    const size_t qrow = (size_t)bb*LL + qw0 + ln15;
    const unsigned char* mrowB = maskb + qrow*(size_t)LL;
    const unsigned char* mrowW = maskb + qrow*(size_t)LL*4;

    const float* kbase = k + (size_t)bb*LL*DD;
    f32x4 kpre[4];
    u32x4 m4c[4], m4n[4];
    unsigned m1c[4], m1n[4];

#define MSK_LOAD(W4, B1, T) { \
    if (fl != 1){ _Pragma("unroll") for (int c_ = 0; c_ < 4; ++c_) \
        W4[c_] = __builtin_nontemporal_load((const u32x4*)(mrowW + ((size_t)(T)*KT + c_*16 + 4*g)*4)); } \
    else        { _Pragma("unroll") for (int c_ = 0; c_ < 4; ++c_) \
        B1[c_] = __builtin_nontemporal_load((const unsigned*)(mrowB + (size_t)(T)*KT + c_*16 + 4*g)); } }

    unsigned* pw = &p_u32[w*512];

    const int T0 = quart * SKT;
    float rs = 0.f;
    K_LOAD4(T0); MSK_LOAD(m4c, m1c, T0);
    for (int tt = 0; tt < SKT; ++tt){
        const int t = T0 + tt;
        __syncthreads();
        K_WRITE4();
        if (tt+1 < SKT){ K_LOAD4(t+1); MSK_LOAD(m4n, m1n, t+1); }
        __syncthreads();
        #pragma unroll
        for (int cg = 0; cg < 4; ++cg){
            f32x4 acc = {0.f, 0.f, 0.f, 0.f};
            QK_MFMA_SW(acc, cg);
            bool k0, k1, k2, k3;
            if (fl != 1){
                u32x4 u = m4c[cg];
                k0 = u[0] != 0u; k1 = u[1] != 0u; k2 = u[2] != 0u; k3 = u[3] != 0u;
            } else {
                unsigned u = m1c[cg];
                k0 = (u & 0xFFu) != 0u;       k1 = (u & 0xFF00u) != 0u;
                k2 = (u & 0xFF0000u) != 0u;   k3 = (u & 0xFF000000u) != 0u;
            }
            float p0 = k0 ? 0.f : __expf(acc[0] * SCALE);
            float p1 = k1 ? 0.f : __expf(acc[1] * SCALE);
            float p2 = k2 ? 0.f : __expf(acc[2] * SCALE);
            float p3 = k3 ? 0.f : __expf(acc[3] * SCALE);
            rs += (p0 + p1) + (p2 + p3);
            if (STOREP){
                const int mp = ((cg*4 + g) + ln15) & 15;
                u32x2 wv = { pk2(p0, p1), pk2(p2, p3) };
                *(u32x2*)(&pw[ln15*32 + mp*2]) = wv;
            }
        }
        if (STOREP){
            // write P~ tile: per instr 4 rows x 128B contiguous bf16 (cached —
            // the PV kernel wants these L2/L3-resident)
            #pragma unroll
            for (int i = 0; i < 4; ++i){
                const int rl = i*4 + g;
                u32x2 pb = *(const u32x2*)(&pw[rl*32 + (((ln15 + rl) & 15)*2)]);
                *(u32x2*)(pS + ((size_t)bb*LL + qw0 + rl)*(size_t)LL + t*KT + ln15*4) = pb;
            }
        }
        #pragma unroll
        for (int c_ = 0; c_ < 4; ++c_){ m4c[c_] = m4n[c_]; m1c[c_] = m1n[c_]; }
    }
    rs += __shfl_xor(rs, 16);
    rs += __shfl_xor(rs, 32);
    if (lane < 16)
        lpart[(size_t)quart*BB*LL + (size_t)bb*LL + qw0 + lane] = rs;
#undef MSK_LOAD
}

// ===== kernel 2 V3b (D-split, half-V staging): attn + out directly =====
__global__ __launch_bounds__(TMAIN, 4) void attn_main_v3(
    const float* __restrict__ v, const unsigned short* __restrict__ pS,
    const float* __restrict__ lpart,
    float* __restrict__ attn, float* __restrict__ out)
{
    __shared__ __attribute__((aligned(16))) unsigned short vT_s[64*64];   // 8 KB (my d-half)

    const int tid  = threadIdx.x;
    const int lane = tid & 63;
    const int ln15 = lane & 15;
    const int g    = lane >> 4;
    const int kr2  = tid >> 4;             // 0..31 (2 k-rows each)
    const int dc   = tid & 15;             // 0..15 (4 local d-cols each)
    const int w    = tid >> 6;

    const int hw   = blockIdx.x;
    const int bidx = (hw & 7) * (NWG_V/8) + (hw >> 3);
    const int bb   = bidx >> 5;
    const int rem  = bidx & 31;
    const int dh   = rem & 1;              // d-half: cols [dh*64, dh*64+64)
    const int qt0  = (rem >> 1) * QTM;
    const int qw0  = qt0 + w*16;

    float invlA[4], invlE[4];
    #pragma unroll
    for (int i = 0; i < 4; ++i){
        float sA = 0.f, sE = 0.f;
        #pragma unroll
        for (int sl = 0; sl < SPLIT_S; ++sl){
            sA += lpart[(size_t)sl*BB*LL + (size_t)bb*LL + qw0 + i*4 + g];
            sE += lpart[(size_t)sl*BB*LL + (size_t)bb*LL + qw0 + 4*g + i];
        }
        invlA[i] = 1.0f / sA;
        invlE[i] = 1.0f / sE;
    }

    const float* vbase = v + (size_t)bb*LL*DD + dh*64;
    f32x4 vh[2];

#define VH_LOAD(T) { \
    _Pragma("unroll") for (int j_ = 0; j_ < 2; ++j_) \
        vh[j_] = *(const f32x4*)(vbase + ((size_t)(T)*KT + kr2*2 + j_)*DD + dc*4); }

#define VH_WRITE() { \
    _Pragma("unroll") for (int cc_ = 0; cc_ < 4; ++cc_){ \
        int d_ = dc*4 + cc_; \
        int key_ = (dc & 7) ^ ((cc_ << 1) & 7); \
        int kk_ = (kr2*2) ^ (8*key_); \
        unsigned pv_ = pk2(vh[0][cc_], vh[1][cc_]); \
        *(unsigned*)(&vT_s[d_*64 + kk_]) = pv_; } }

    const unsigned short* prow = pS + ((size_t)bb*LL + qw0 + ln15)*(size_t)LL;
    size_t arow_off[4];
    #pragma unroll
    for (int i = 0; i < 4; ++i)
        arow_off[i] = ((size_t)bb*LL + qw0 + i*4 + g)*(size_t)LL;

    f32x4 oacc[4];
    #pragma unroll
    for (int d8 = 0; d8 < 4; ++d8) oacc[d8] = (f32x4){0.f, 0.f, 0.f, 0.f};

    bf16x8 pa0c, pa1c, pa0n, pa1n;

    VH_LOAD(0);
    pa0c = *(const bf16x8*)(prow + 8*g);
    pa1c = *(const bf16x8*)(prow + 32 + 8*g);
    for (int t = 0; t < NT; ++t){
        __syncthreads();
        VH_WRITE();
        if (t+1 < NT){
            VH_LOAD(t+1);
            pa0n = *(const bf16x8*)(prow + (size_t)(t+1)*KT + 8*g);
            pa1n = *(const bf16x8*)(prow + (size_t)(t+1)*KT + 32 + 8*g);
        }
        __syncthreads();
        if ((t >> 4) == dh){
            #pragma unroll
            for (int i = 0; i < 4; ++i){
                u32x2 pb = *(const u32x2*)(pS + arow_off[i] + (size_t)t*KT + ln15*4);
                f32x4 val = { bf2f((unsigned short)(pb[0] & 0xFFFFu)) * invlA[i],
                              bf2f((unsigned short)(pb[0] >> 16))     * invlA[i],
                              bf2f((unsigned short)(pb[1] & 0xFFFFu)) * invlA[i],
                              bf2f((unsigned short)(pb[1] >> 16))     * invlA[i] };
                __builtin_nontemporal_store(val,
                    (f32x4*)(attn + arow_off[i] + (size_t)t*KT + ln15*4));
            }
        }
        #pragma unroll
        for (int d8 = 0; d8 < 4; ++d8){
            const int d_ = d8*16 + ln15;                 // local d
            const unsigned short* vb = &vT_s[d_*64];
            const int ev = 8*(((4*d8 + (ln15 >> 2)) & 7) ^ ((ln15 & 3) << 1));
            bf16x8 b0 = *(const bf16x8*)(vb + ((g*8) ^ ev));
            bf16x8 b1 = *(const bf16x8*)(vb + ((32 + g*8) ^ ev));
            oacc[d8] = __builtin_amdgcn_mfma_f32_16x16x32_bf16(pa0c, b0, oacc[d8], 0, 0, 0);
            oacc[d8] = __builtin_amdgcn_mfma_f32_16x16x32_bf16(pa1c, b1, oacc[d8], 0, 0, 0);
        }
        pa0c = pa0n; pa1c = pa1n;
    }
#undef VH_LOAD
#undef VH_WRITE

    #pragma unroll
    for (int d8 = 0; d8 < 4; ++d8){
        #pragma unroll
        for (int r = 0; r < 4; ++r){
            out[((size_t)bb*LL + qw0 + 4*g + r)*DD + dh*64 + d8*16 + ln15]
                = oacc[d8][r] * invlE[r];
        }
    }
}

// ===== old kernel 2 (r11-proven fallback): QK in-kernel, K-split =====
template<int NS>
__global__ __launch_bounds__(TMAIN, 4) void attn_main(
    const float* __restrict__ q, const float* __restrict__ k, const float* __restrict__ v,
    const u64* __restrict__ mb, const float* __restrict__ lpart,
    float* __restrict__ attn, float* __restrict__ pO)
{
    __shared__ __attribute__((aligned(16))) unsigned short k_s[KT*DD];
    __shared__ __attribute__((aligned(16))) unsigned short vT_s[DD*KT];
    __shared__ __attribute__((aligned(16))) unsigned p_u32[8*512];

    const int tid  = threadIdx.x;
    const int w    = tid >> 6;
    const int lane = tid & 63;
    const int ln15 = lane & 15;
    const int g    = lane >> 4;
    const int r0   = tid >> 5;
    const int c4   = tid & 31;

    const int NWGM = BB*NS*(LL/QTM);
    const int hw   = blockIdx.x;
    const int bidx = (hw & 7) * (NWGM/8) + (hw >> 3);
    const int perb = NS*(LL/QTM);
    const int bb   = bidx / perb;
    const int rem  = bidx % perb;
    const int part = rem >> 4;
    const int qt0  = (rem & 15) * QTM;
    const int qw0  = qt0 + w*16;

    bf16x8 qa[4];
    Q_FRAGS();

    const size_t qrow = (size_t)bb*LL + qw0 + ln15;
    const u64* mrow_bits = mb + qrow * NT;
    float invl;
    {
        float s = 0.f;
        #pragma unroll
        for (int sl = 0; sl < SPLIT_S; ++sl)
            s += lpart[(size_t)sl*BB*LL + qrow];
        invl = 1.0f / s;
    }

    const float* kbase = k + (size_t)bb*LL*DD;
    const float* vbase = v + (size_t)bb*LL*DD;
    f32x4 kpre[4];
    f32x4 vpre[4];
    u64 mc = 0, mn = 0;

    f32x4 oacc[8];
    #pragma unroll
    for (int d8 = 0; d8 < 8; ++d8) oacc[d8] = (f32x4){0.f, 0.f, 0.f, 0.f};

    unsigned* pw = &p_u32[w*512];

    const int HKTN = NT/NS;
    const int T0 = part * HKTN;
    K_LOAD4(T0); V_LOAD4(T0); mc = mrow_bits[T0];
    for (int tt = 0; tt < HKTN; ++tt){
        const int t = T0 + tt;
        __syncthreads();
        K_WRITE4(); V_WRITE4();
        if (tt+1 < HKTN){ K_LOAD4(t+1); V_LOAD4(t+1); mn = mrow_bits[t+1]; }
        __syncthreads();
        #pragma unroll
        for (int cg = 0; cg < 4; ++cg){
            f32x4 acc = {0.f, 0.f, 0.f, 0.f};
            QK_MFMA_SW(acc, cg);
            const int kb0 = cg*16 + 4*g;
            const unsigned nib = (unsigned)(mc >> kb0) & 0xFu;
            f32x4 pv;
            #pragma unroll
            for (int r = 0; r < 4; ++r)
                pv[r] = ((nib >> r) & 1u) ? 0.f : __expf(acc[r] * SCALE) * invl;
            const int m  = cg*4 + g;
            const int mp = (m + ln15) & 15;
            u32x2 wv = { pk2(pv[0], pv[1]), pk2(pv[2], pv[3]) };
            *(u32x2*)(&pw[ln15*32 + mp*2]) = wv;
        }
        #pragma unroll
        for (int it = 0; it < 4; ++it){
            const int rl = it*4 + g;
            u32x2 pb = *(const u32x2*)(&pw[rl*32 + (((ln15 + rl) & 15)*2)]);
            f32x4 val = { bf2f((unsigned short)(pb[0] & 0xFFFFu)),
                          bf2f((unsigned short)(pb[0] >> 16)),
                          bf2f((unsigned short)(pb[1] & 0xFFFFu)),
                          bf2f((unsigned short)(pb[1] >> 16)) };
            __builtin_nontemporal_store(val,
                (f32x4*)(attn + ((size_t)bb*LL + qw0 + rl)*(size_t)LL + t*KT + ln15*4));
        }
        const unsigned* prow_ = &pw[ln15*32];
        u32x2 a00 = *(const u32x2*)(&prow_[(((2*g  ) + ln15) & 15)*2]);
        u32x2 a01 = *(const u32x2*)(&prow_[(((2*g+1) + ln15) & 15)*2]);
        u32x2 a10 = *(const u32x2*)(&prow_[(((8+2*g ) + ln15) & 15)*2]);
        u32x2 a11 = *(const u32x2*)(&prow_[(((9+2*g ) + ln15) & 15)*2]);
        union { unsigned u[4]; bf16x8 v8; } A0, A1;
        A0.u[0]=a00[0]; A0.u[1]=a00[1]; A0.u[2]=a01[0]; A0.u[3]=a01[1];
        A1.u[0]=a10[0]; A1.u[1]=a10[1]; A1.u[2]=a11[0]; A1.u[3]=a11[1];
        const bf16x8 pa0 = A0.v8, pa1 = A1.v8;
        #pragma unroll
        for (int d8 = 0; d8 < 8; ++d8){
            const int d = d8*16 + ln15;
            const unsigned short* vb = &vT_s[d*KT];
            const int ev = 8*((((4*d8 + (ln15 >> 2)) & 7)) ^ ((ln15 & 3) << 1));
            bf16x8 b0 = *(const bf16x8*)(vb + ((g*8) ^ ev));
            bf16x8 b1 = *(const bf16x8*)(vb + ((32 + g*8) ^ ev));
            oacc[d8] = __builtin_amdgcn_mfma_f32_16x16x32_bf16(pa0, b0, oacc[d8], 0, 0, 0);
            oacc[d8] = __builtin_amdgcn_mfma_f32_16x16x32_bf16(pa1, b1, oacc[d8], 0, 0, 0);
        }
        mc = mn;
    }

    float* po = pO + (size_t)part*BB*LL*DD;
    #pragma unroll
    for (int d8 = 0; d8 < 8; ++d8){
        #pragma unroll
        for (int r = 0; r < 4; ++r){
            po[((size_t)bb*LL + qw0 + 4*g + r)*DD + d8*16 + ln15] = oacc[d8][r];
        }
    }
}

template<int NS>
__global__ void combine_out(const float* __restrict__ pO, float* __restrict__ out){
    size_t i = ((size_t)blockIdx.x*THREADS + threadIdx.x) * 4;
    f32x4 s = *(const f32x4*)(pO + i);
    #pragma unroll
    for (int sl = 1; sl < NS; ++sl)
        s += *(const f32x4*)(pO + (size_t)sl*BB*LL*DD + i);
    *(f32x4*)(out + i) = s;
}

// ================= fallback: fused two-pass (unswapped) =================
template<int USE_BITS>
__global__ __launch_bounds__(THREADS, 3) void attn_fused(
    const float* __restrict__ q, const float* __restrict__ k, const float* __restrict__ v,
    const unsigned char* __restrict__ maskb, const int* __restrict__ flagp,
    const u64* __restrict__ mb,
    float* __restrict__ out, float* __restrict__ attn)
{
    __shared__ __attribute__((aligned(16))) unsigned short k_s[KT*DD];
    __shared__ __attribute__((aligned(16))) unsigned short vT_s[DD*KT];
    __shared__ __attribute__((aligned(16))) unsigned short p_bf[4*16*64];

    const int tid  = threadIdx.x;
    const int w    = tid >> 6;
    const int lane = tid & 63;
    const int ln15 = lane & 15;
    const int g    = lane >> 4;
    const int r0   = tid >> 5;
    const int c4   = tid & 31;

    const int bidx = blockIdx.x;
    const int bb   = bidx >> 5;
    const int qt0  = (bidx & 31) * QT;
    const int qw0  = qt0 + w*16;

    int msh = 0, madd = 0;
    if (!USE_BITS){
        const int mflag = flagp[0];
        msh  = (mflag == 1) ? 0 : 2;
        madd = (mflag == 2) ? 3 : 0;
    }

    bf16x8 qa[4];
    Q_FRAGS();

    size_t mrow[4];
    const u64* mbB = mb + ((size_t)bb*LL + qw0 + 4*g) * NT;
    #pragma unroll
    for (int r = 0; r < 4; ++r)
        mrow[r] = ((size_t)bb*LL + qw0 + 4*g + r) * (size_t)LL;

    const float* kbase = k + (size_t)bb*LL*DD;
    const float* vbase = v + (size_t)bb*LL*DD;

    f32x4 kpre[8];
    u64 mc[4] = {0,0,0,0}, mn[4] = {0,0,0,0};

    float rs[4] = {0.f, 0.f, 0.f, 0.f};
    K_LOAD(0); if (USE_BITS) M_LOADB(mc, 0);
    for (int t = 0; t < NT; ++t){
        __syncthreads();
        K_WRITE();
        if (t+1 < NT){ K_LOAD(t+1); if (USE_BITS) M_LOADB(mn, t+1); }
        __syncthreads();
        #pragma unroll
        for (int cg = 0; cg < 4; ++cg){
            f32x4 acc = {0.f, 0.f, 0.f, 0.f};
            QK_MFMA(acc, cg);
            const int kc = cg*16 + ln15;
            #pragma unroll
            for (int r = 0; r < 4; ++r){
                bool msk;
                if (USE_BITS) msk = (mc[r] >> kc) & 1ull;
                else          msk = maskb[((mrow[r] + t*KT + kc) << msh) + madd] != 0;
                rs[r] += msk ? 0.f : __expf(acc[r] * SCALE);
            }
        }
        if (USE_BITS){
            #pragma unroll
            for (int r = 0; r < 4; ++r) mc[r] = mn[r];
        }
    }

    float invl[4];
    #pragma unroll
    for (int r = 0; r < 4; ++r){
        float s = rs[r];
        s += __shfl_xor(s, 1); s += __shfl_xor(s, 2);
        s += __shfl_xor(s, 4); s += __shfl_xor(s, 8);
        invl[r] = 1.0f / s;
    }

    f32x4 oacc[8];
    #pragma unroll
    for (int d8 = 0; d8 < 8; ++d8) oacc[d8] = (f32x4){0.f, 0.f, 0.f, 0.f};

    unsigned short* pw = &p_bf[w*1024];
    const int w4 = ln15 >> 2;

    K_LOAD(0); if (USE_BITS) M_LOADB(mc, 0);
    for (int t = 0; t < NT; ++t){
        __syncthreads();
        K_WRITE();
        V_STAGE(t);
        if (t+1 < NT){ K_LOAD(t+1); if (USE_BITS) M_LOADB(mn, t+1); }
        __syncthreads();
        #pragma unroll
        for (int cg = 0; cg < 4; ++cg){
            f32x4 acc = {0.f, 0.f, 0.f, 0.f};
            QK_MFMA(acc, cg);
            const int kc = cg*16 + ln15;
            #pragma unroll
            for (int r = 0; r < 4; ++r){
                bool msk;
                if (USE_BITS) msk = (mc[r] >> kc) & 1ull;
                else          msk = maskb[((mrow[r] + t*KT + kc) << msh) + madd] != 0;
                float p = msk ? 0.f : __expf(acc[r] * SCALE) * invl[r];
                pw[(4*g + r)*64 + (kc ^ (g << 4))] = f2bf(p);
            }
        }
        #pragma unroll
        for (int it = 0; it < 4; ++it){
            int row = it*4 + g;
            u16x4 pb = *(const u16x4*)(&pw[row*64 + ((ln15*4) ^ (it << 4))]);
            f32x4 val = { bf2f(pb[0]), bf2f(pb[1]), bf2f(pb[2]), bf2f(pb[3]) };
            *(f32x4*)(&attn[((size_t)bb*LL + qw0 + row)*(size_t)LL + t*KT + ln15*4]) = val;
        }
        const unsigned short* par = pw + ln15*64;
        bf16x8 pa0 = *(const bf16x8*)(par + ((g*8)      ^ (w4 << 4)));
        bf16x8 pa1 = *(const bf16x8*)(par + ((32 + g*8) ^ (w4 << 4)));
        #pragma unroll
        for (int d8 = 0; d8 < 8; ++d8){
            const int d = d8*16 + ln15;
            const unsigned short* vb = &vT_s[d*KT];
            const int ev = 8*((4*d8 + (ln15 >> 2)) & 7);
            bf16x8 b0 = *(const bf16x8*)(vb + ((g*8) ^ ev));
            bf16x8 b1 = *(const bf16x8*)(vb + ((32 + g*8) ^ ev));
            oacc[d8] = __builtin_amdgcn_mfma_f32_16x16x32_bf16(pa0, b0, oacc[d8], 0, 0, 0);
            oacc[d8] = __builtin_amdgcn_mfma_f32_16x16x32_bf16(pa1, b1, oacc[d8], 0, 0, 0);
        }
        if (USE_BITS){
            #pragma unroll
            for (int r = 0; r < 4; ++r) mc[r] = mn[r];
        }
    }

    #pragma unroll
    for (int d8 = 0; d8 < 8; ++d8){
        #pragma unroll
        for (int r = 0; r < 4; ++r){
            out[((size_t)bb*LL + qw0 + 4*g + r)*DD + d8*16 + ln15] = oacc[d8][r];
        }
    }
}

extern "C" void kernel_launch(void* const* d_in, const int* in_sizes, int n_in,
                              void* d_out, int out_size, void* d_ws, size_t ws_size,
                              hipStream_t stream)
{
    const float* q = (const float*)d_in[0];
    const float* k = (const float*)d_in[1];
    const float* v = (const float*)d_in[2];
    const unsigned char* mask = (const unsigned char*)d_in[3];

    float* out  = (float*)d_out;
    float* attn = out + (size_t)BB*LL*DD;

    const size_t oO      = (size_t)BB*LL*DD*sizeof(float);         // 16.8 MB / partial
    const size_t bits_sz = (size_t)BB*LL*NT*sizeof(u64);           // 8.39 MB
    const size_t off_lp  = 256 + bits_sz;
    const size_t lp_sz   = (size_t)SPLIT_S*BB*LL*sizeof(float);    // 512 KB
    const size_t off_pS  = off_lp + lp_sz;
    const size_t pS_sz   = (size_t)BB*LL*LL*sizeof(unsigned short);// 134.2 MB
    const size_t need_v3 = off_pS + pS_sz;                         // ~143.3 MB
    const size_t off_pOo = off_pS;
    const size_t need_o4 = off_pOo + 4*oO;                         // ~75.9 MB (r11-proven)
    const size_t need_o2 = off_pOo + 2*oO;                         // ~42.4 MB (r10-proven)
    const size_t need_bits = off_lp;

    int*   flag  = (int*)d_ws;
    u64*   mb    = (u64*)((char*)d_ws + 256);
    float* lpart = (float*)((char*)d_ws + off_lp);
    unsigned short* pS = (unsigned short*)((char*)d_ws + off_pS);
    float* pOo   = (float*)((char*)d_ws + off_pOo);

    if (ws_size >= need_v3){
        scores<1><<<NWG_S, TMAIN, 0, stream>>>(q, k, mask, lpart, pS);
        attn_main_v3<<<NWG_V, TMAIN, 0, stream>>>(v, pS, lpart, attn, out);
    } else if (ws_size >= need_o4){
        prepack_mask<<<(BB*LL*NT)/THREADS, THREADS, 0, stream>>>(mask, mb);
        scores<0><<<NWG_S, TMAIN, 0, stream>>>(q, k, mask, lpart, pS);
        attn_main<4><<<BB*4*(LL/QTM), TMAIN, 0, stream>>>(q, k, v, mb, lpart, attn, pOo);
        combine_out<4><<<(BB*LL*DD)/(4*THREADS), THREADS, 0, stream>>>(pOo, out);
    } else if (ws_size >= need_o2){
        prepack_mask<<<(BB*LL*NT)/THREADS, THREADS, 0, stream>>>(mask, mb);
        scores<0><<<NWG_S, TMAIN, 0, stream>>>(q, k, mask, lpart, pS);
        attn_main<2><<<BB*2*(LL/QTM), TMAIN, 0, stream>>>(q, k, v, mb, lpart, attn, pOo);
        combine_out<2><<<(BB*LL*DD)/(4*THREADS), THREADS, 0, stream>>>(pOo, out);
    } else if (ws_size >= need_bits){
        detect_mask<<<1, 64, 0, stream>>>((const unsigned*)mask, flag);
        prepack_mask<<<(BB*LL*NT)/THREADS, THREADS, 0, stream>>>(mask, mb);
        attn_fused<1><<<NWG, THREADS, 0, stream>>>(q, k, v, mask, flag, mb, out, attn);
    } else {
        detect_mask<<<1, 64, 0, stream>>>((const unsigned*)mask, flag);
        attn_fused<0><<<NWG, THREADS, 0, stream>>>(q, k, v, mask, flag, mb, out, attn);
    }
}